// Round 6
// baseline (38.178 us; speedup 1.0000x reference)
//
#include <hip/hip_runtime.h>
#include <hip/hip_bf16.h>

#define F_FIELDS 39
#define VOCAB    100000
#define EMB      16
#define BATCH    16384
#define H1       32
#define H2       32
#define KSTEPS   20   /* K = 640 = 20 x 32 */
#define KPW      5    /* MFMA k-steps per wave (4-way split) */
#define GPW      10   /* gather fields per wave (4 waves x 10 = 40 >= 39) */

typedef __bf16 bf16x8 __attribute__((ext_vector_type(8)));
typedef __bf16 bf16x4 __attribute__((ext_vector_type(4)));
typedef float  f32x4  __attribute__((ext_vector_type(4)));

// ---------------- pre-kernel: W1 (f32, [624][32]) -> bf16 MFMA-B fragments in d_ws ----------------
// frag id = (kstep*2 + nhalf)*64 + lane; element j: k = kstep*32 + (lane>>4)*8 + j, n = nhalf*16 + (lane&15)
__global__ __launch_bounds__(256) void swizzle_w1_kernel(const float* __restrict__ W1,
                                                         __bf16* __restrict__ ws)
{
    int fidx = blockIdx.x * 256 + threadIdx.x;
    if (fidx >= KSTEPS * 2 * 64) return;
    int lane = fidx & 63;
    int nh   = (fidx >> 6) & 1;
    int ks   = fidx >> 7;
    int k0   = ks * 32 + (lane >> 4) * 8;
    int n    = nh * 16 + (lane & 15);
    __bf16 vals[8];
    #pragma unroll
    for (int j = 0; j < 8; ++j) {
        int k = k0 + j;
        vals[j] = (k < F_FIELDS * EMB) ? (__bf16)W1[k * H1 + n] : (__bf16)0.0f;
    }
    *reinterpret_cast<bf16x8*>(&ws[fidx * 8]) = *reinterpret_cast<const bf16x8*>(vals);
}

// ---------------- main kernel ----------------
// Block = 256 threads = 4 waves = 16 samples.
// Gather phase: lane (s = l&15, q = l>>4) loads QUARTER q (16B) of row (sample s, field f),
//   f = h + 4*i (i = 0..9) -> ONE instruction covers 16 rows, 4 lanes coalesce per 64B row.
//   FM stats accumulated in f32 per lane (positions q*4..q*4+3); scaled row -> eds (bf16).
// MFMA phase: wave h does ksteps ks = h+4j; A-frag lane (s,qa): field 2ks+(qa>>1),
//   positions (qa&1)*8..+7  ->  one ds_read_b128 from eds[f][s][p0].
__global__ __launch_bounds__(256, 4) void deepfm_main(
    const int*   __restrict__ Xi,  const float* __restrict__ Xv,
    const float* __restrict__ emb1,const float* __restrict__ emb2,
    const __bf16* __restrict__ wsW1,
    const float* __restrict__ b1,  const float* __restrict__ W2,
    const float* __restrict__ b2,  const float* __restrict__ bias,
    float* __restrict__ out)
{
    __shared__ int   sXi[16 * F_FIELDS];                 // 2.4 KB
    __shared__ float sXv[16 * F_FIELDS];                 // 2.4 KB
    __shared__ __align__(16) __bf16 eds[40][16][16];     // 20 KB  scaled rows (bf16), [field][sample][pos]
    __shared__ float pacc[4][16][32];                    // 8 KB   per-wave layer-1 partials
    __shared__ float sbuf[4][16][16];                    // 4 KB   per-wave FM s-vector partials
    __shared__ float qbuf[4][16];                        // per-wave FM sq-sum partials
    __shared__ float fbuf[4][16];                        // per-wave first-order partials
    __shared__ float W2s[H1 * H2];                       // 4 KB
    __shared__ float hs[16][32];                         // 2 KB   relu(layer-1)

    const int t    = threadIdx.x;
    const int h    = t >> 6;           // wave id
    const int l    = t & 63;
    const int s    = l & 15;           // sample within block
    const int q    = l >> 4;           // quarter / frag row-group
    const int blk  = blockIdx.x;

    // ---- coalesced stage of this block's Xi/Xv rows ----
    {
        const int base = blk * 16 * F_FIELDS;
        for (int i = t; i < 16 * F_FIELDS; i += 256) {
            sXi[i] = Xi[base + i];
            sXv[i] = Xv[base + i];
        }
    }
    reinterpret_cast<float4*>(W2s)[t] = reinterpret_cast<const float4*>(W2)[t];
    __syncthreads();

    // ---- issue all emb2 quarter-gathers (10 x 16B per lane, plain cached loads) ----
    f32x4 g[GPW]; float xvg[GPW];
    #pragma unroll
    for (int i = 0; i < GPW; ++i) {
        int f  = h + 4 * i;                   // 0..39
        bool v = (f < F_FIELDS);
        int fi = v ? f : 0;
        int idx = sXi[s * F_FIELDS + fi];
        xvg[i]  = v ? sXv[s * F_FIELDS + fi] : 0.0f;
        const f32x4* rp = reinterpret_cast<const f32x4*>(emb2 + (fi * VOCAB + idx) * EMB) + q;
        g[i] = *rp;
    }
    // ---- issue emb1 gathers: fields f = 4h+q+16i (plain cached loads) ----
    float e1v[3], xvf[3];
    #pragma unroll
    for (int i = 0; i < 3; ++i) {
        int f  = 4 * h + q + 16 * i;
        bool v = (f < F_FIELDS);
        int fi = v ? f : 0;
        int idx = sXi[s * F_FIELDS + fi];
        xvf[i] = v ? sXv[s * F_FIELDS + fi] : 0.0f;
        e1v[i] = emb1[fi * VOCAB + idx];
    }

    // ---- consume gathers: FM stats (f32) + scaled bf16 rows -> LDS ----
    float sa4[4] = {0.f, 0.f, 0.f, 0.f};
    float qq = 0.f;
    #pragma unroll
    for (int i = 0; i < GPW; ++i) {
        int f = h + 4 * i;
        float xv = xvg[i];
        float e0 = g[i][0] * xv, e1 = g[i][1] * xv, e2 = g[i][2] * xv, e3 = g[i][3] * xv;
        sa4[0] += e0; sa4[1] += e1; sa4[2] += e2; sa4[3] += e3;
        qq += e0*e0 + e1*e1 + e2*e2 + e3*e3;
        bf16x4 bv = { (__bf16)e0, (__bf16)e1, (__bf16)e2, (__bf16)e3 };
        *reinterpret_cast<bf16x4*>(&eds[f][s][q * 4]) = bv;   // f=39 pad row: zeros (xv=0)
    }

    // FM partials: s-vector quarter per lane; sq-sum reduced over quarters
    *reinterpret_cast<float4*>(&sbuf[h][s][q * 4]) = make_float4(sa4[0], sa4[1], sa4[2], sa4[3]);
    qq += __shfl_xor(qq, 16);
    qq += __shfl_xor(qq, 32);
    if (l < 16) qbuf[h][s] = qq;

    // first-order partial
    float facc = 0.f;
    #pragma unroll
    for (int i = 0; i < 3; ++i) facc += e1v[i] * xvf[i];
    facc += __shfl_xor(facc, 16);
    facc += __shfl_xor(facc, 32);
    if (l < 16) fbuf[h][s] = facc;

    __syncthreads();   // eds ready

    // ---- MFMA phase: wave h does ksteps ks = h + 4j ----
    const bf16x8* wsf = reinterpret_cast<const bf16x8*>(wsW1);
    f32x4 acc0 = {0.f,0.f,0.f,0.f}, acc1 = {0.f,0.f,0.f,0.f};
    #pragma unroll
    for (int j = 0; j < KPW; ++j) {
        int ks = h + 4 * j;                    // 0..19
        int f  = 2 * ks + (q >> 1);            // 0..39 (39 = zero pad row)
        int p0 = (q & 1) * 8;
        bf16x8 afr = *reinterpret_cast<const bf16x8*>(&eds[f][s][p0]);
        bf16x8 b0  = wsf[(ks * 2 + 0) * 64 + l];
        bf16x8 b1f = wsf[(ks * 2 + 1) * 64 + l];
        acc0 = __builtin_amdgcn_mfma_f32_16x16x32_bf16(afr, b0,  acc0, 0, 0, 0);
        acc1 = __builtin_amdgcn_mfma_f32_16x16x32_bf16(afr, b1f, acc1, 0, 0, 0);
    }

    // ---- layer-1 partials -> LDS (b1 folded into wave 0) ----
    float badd0 = (h == 0) ? b1[s]      : 0.f;
    float badd1 = (h == 0) ? b1[16 + s] : 0.f;
    #pragma unroll
    for (int r = 0; r < 4; ++r) {
        int row = q * 4 + r;                   // C-frag: row = q*4+r, col = lane&15
        pacc[h][row][s]      = acc0[r] + badd0;
        pacc[h][row][16 + s] = acc1[r] + badd1;
    }
    __syncthreads();

    // ---- h = relu(sum of partials) ----
    {
        int ss = t >> 4, c = t & 15;
        hs[ss][c]      = fmaxf(pacc[0][ss][c]      + pacc[1][ss][c]      + pacc[2][ss][c]      + pacc[3][ss][c],      0.f);
        hs[ss][c + 16] = fmaxf(pacc[0][ss][c + 16] + pacc[1][ss][c + 16] + pacc[2][ss][c + 16] + pacc[3][ss][c + 16], 0.f);
    }
    __syncthreads();

    // ---- final: 16 threads per sample ----
    const int so = t >> 4;
    const int u  = t & 15;

    float sv = sbuf[0][so][u] + sbuf[1][so][u] + sbuf[2][so][u] + sbuf[3][so][u];
    float s2 = sv * sv;

    float a0 = b2[2 * u], a1 = b2[2 * u + 1];
    #pragma unroll
    for (int i = 0; i < H1; ++i) {
        float hv = hs[so][i];
        a0 += hv * W2s[i * H2 + 2 * u];
        a1 += hv * W2s[i * H2 + 2 * u + 1];
    }
    float psum = fmaxf(a0, 0.f) + fmaxf(a1, 0.f);

    psum += __shfl_xor(psum, 1);  s2 += __shfl_xor(s2, 1);
    psum += __shfl_xor(psum, 2);  s2 += __shfl_xor(s2, 2);
    psum += __shfl_xor(psum, 4);  s2 += __shfl_xor(s2, 4);
    psum += __shfl_xor(psum, 8);  s2 += __shfl_xor(s2, 8);

    if (u == 0) {
        float qtot = qbuf[0][so] + qbuf[1][so] + qbuf[2][so] + qbuf[3][so];
        float ftot = fbuf[0][so] + fbuf[1][so] + fbuf[2][so] + fbuf[3][so];
        out[blk * 16 + so] = psum + 0.5f * (s2 - qtot) + ftot + bias[0];
    }
}

extern "C" void kernel_launch(void* const* d_in, const int* in_sizes, int n_in,
                              void* d_out, int out_size, void* d_ws, size_t ws_size,
                              hipStream_t stream) {
    const int*   Xi   = (const int*)  d_in[0];
    const float* Xv   = (const float*)d_in[1];
    const float* emb1 = (const float*)d_in[2];
    const float* emb2 = (const float*)d_in[3];
    const float* W1   = (const float*)d_in[4];
    const float* b1   = (const float*)d_in[5];
    const float* W2   = (const float*)d_in[6];
    const float* b2   = (const float*)d_in[7];
    const float* bias = (const float*)d_in[8];
    float* out = (float*)d_out;
    __bf16* ws = (__bf16*)d_ws;

    swizzle_w1_kernel<<<(KSTEPS*2*64 + 255)/256, 256, 0, stream>>>(W1, ws);
    deepfm_main<<<BATCH/16, 256, 0, stream>>>(Xi, Xv, emb1, emb2, ws, b1, W2, b2, bias, out);
}